// Round 11
// baseline (180.907 us; speedup 1.0000x reference)
//
#include <hip/hip_runtime.h>
#include <hip/hip_bf16.h>
#include <math.h>

// Problem constants (from the reference)
#define NALT      8
#define BDIM      8
#define CDIM      4
#define RDIM      512
#define OUT_HALF  (BDIM * CDIM * RDIM * NALT)   // 131072 floats
#define OUT_TOTAL (2 * OUT_HALF)                // 262144 floats [MC | SC]

#define NBUCKET   32          // bucket = b*4+c
#define BLK_ATOMS 1024        // atoms per block (256 thr x AITER)
#define AITER     4
#define NWAVE     4           // 256 threads / 64
#define LSLOTS    8192        // accum LDS tile: bb(2)*r(512)*alt(8) f32 = 32 KiB

// ws layout (runtime offsets, 256B-aligned):
//   hdr  u16 [nblocks][64]   (0..32 = exclusive bucket offsets in block)
//   lidx u16 [nblocks][1024]
//   vals uint4[nblocks][1024]
//   partial f32 [NBUCKET*nsplit][LSLOTS]
//   done u32 [NBUCKET]       (zeroed each call)

__device__ __forceinline__ unsigned int pack_bf16_2(float a, float b) {
    unsigned int ua = __float_as_uint(a);
    unsigned int ub = __float_as_uint(b);
    ua = (ua + 0x7fffu + ((ua >> 16) & 1u)) >> 16;   // round-to-nearest-even
    ub = (ub + 0x7fffu + ((ub >> 16) & 1u)) >> 16;
    return ua | (ub << 16);
}

// K1: fused count+scan+compact. One desc read. All global loads issue up
// front; values computed (f/m consumed) BEFORE the first barrier so the
// barrier-drain waits on an already-consumed stream. Records staged in LDS
// (scatter absorbed), then block-major coalesced copy-out (R8/R10 evidence:
// block-major coalesced stores = zero write inflation).
__global__ void __launch_bounds__(256) vdw_fused_kernel(
    const int4*   __restrict__ desc,
    const int4*   __restrict__ mask,
    const float4* __restrict__ facc,
    const float*  __restrict__ props,
    const float*  __restrict__ weight,
    unsigned short* __restrict__ hdrArr,   // [nblocks][64]
    unsigned short* __restrict__ lidxArr,  // [nblocks][1024]
    uint4*        __restrict__ valArr,     // [nblocks][1024]
    int n)
{
    __shared__ unsigned int   cw[NWAVE][NBUCKET];
    __shared__ unsigned int   tot[NBUCKET];
    __shared__ unsigned int   base[NBUCKET + 1];
    __shared__ unsigned short s_lidx[BLK_ATOMS];
    __shared__ uint4          s_val[BLK_ATOMS];

    const int tid  = threadIdx.x;
    const int w    = tid >> 6;
    const int lane = tid & 63;
    if (lane < NBUCKET) cw[w][lane] = 0;   // wave-lockstep, ordered before this wave's atomics

    // ---- issue ALL global loads up front (max MLP) ----
    const int a0 = blockIdx.x * BLK_ATOMS;
    int4   d_[AITER];
    float4 f0_[AITER], f1_[AITER];
    int4   m0_[AITER], m1_[AITER];
    bool   ok[AITER];
    #pragma unroll
    for (int it = 0; it < AITER; ++it) {
        const int a  = a0 + it * 256 + tid;
        ok[it] = (a < n);
        const int aa = ok[it] ? a : (n - 1);
        d_[it]  = desc[aa];
        f0_[it] = facc[aa * 2 + 0];
        f1_[it] = facc[aa * 2 + 1];
        m0_[it] = mask[aa * 2 + 0];
        m1_[it] = mask[aa * 2 + 1];
    }
    const float scale = (1.0f - tanhf(weight[0])) * 0.3f;

    // ---- histogram (consumes desc only; f/m still in flight) ----
    int bkt[AITER];
    int lidx[AITER];
    #pragma unroll
    for (int it = 0; it < AITER; ++it) {
        const int4 d = d_[it];
        bkt[it] = -1;
        if (ok[it] && d.w != -1) {
            bkt[it]  = d.y * CDIM + d.z;
            lidx[it] = ((d.x < 4) ? 0 : 4096) + d.w * 8;
            atomicAdd(&cw[w][bkt[it]], 1u);
        }
    }

    // ---- compute packed values (consumes f/m + props gather) ----
    uint4 rv[AITER];
    #pragma unroll
    for (int it = 0; it < AITER; ++it) {
        if (bkt[it] < 0) continue;
        const float vs = props[d_[it].x * 8] * scale;
        const float4 f0 = f0_[it], f1 = f1_[it];
        const int4   m0 = m0_[it], m1 = m1_[it];
        const float v0 = m0.x ? vs * fmaxf(f0.x, 0.0f) : 0.0f;
        const float v1 = m0.y ? vs * fmaxf(f0.y, 0.0f) : 0.0f;
        const float v2 = m0.z ? vs * fmaxf(f0.z, 0.0f) : 0.0f;
        const float v3 = m0.w ? vs * fmaxf(f0.w, 0.0f) : 0.0f;
        const float v4 = m1.x ? vs * fmaxf(f1.x, 0.0f) : 0.0f;
        const float v5 = m1.y ? vs * fmaxf(f1.y, 0.0f) : 0.0f;
        const float v6 = m1.z ? vs * fmaxf(f1.z, 0.0f) : 0.0f;
        const float v7 = m1.w ? vs * fmaxf(f1.w, 0.0f) : 0.0f;
        rv[it] = make_uint4(pack_bf16_2(v0, v1), pack_bf16_2(v2, v3),
                            pack_bf16_2(v4, v5), pack_bf16_2(v6, v7));
    }
    __syncthreads();   // b1: stream fully consumed by now

    // ---- in-block scan: per-wave prefixes + bucket bases ----
    if (tid < NBUCKET) {
        unsigned int s = 0;
        #pragma unroll
        for (int ww = 0; ww < NWAVE; ++ww) {
            const unsigned int c = cw[ww][tid];
            cw[ww][tid] = s;           // per-wave start offset within bucket
            s += c;
        }
        tot[tid] = s;
    }
    __syncthreads();   // b2
    if (tid == 0) {
        unsigned int run = 0;
        #pragma unroll
        for (int j = 0; j < NBUCKET; ++j) { base[j] = run; run += tot[j]; }
        base[NBUCKET] = run;
    }
    __syncthreads();   // b3

    // ---- stage into LDS at bucket-grouped positions ----
    #pragma unroll
    for (int it = 0; it < AITER; ++it) {
        if (bkt[it] < 0) continue;
        const unsigned int pos = base[bkt[it]] + atomicAdd(&cw[w][bkt[it]], 1u);
        s_lidx[pos] = (unsigned short)lidx[it];
        s_val[pos]  = rv[it];
    }
    __syncthreads();   // b4 (LDS-only)

    // ---- coalesced block-major copy-out ----
    if (tid <= NBUCKET)
        hdrArr[blockIdx.x * 64 + tid] = (unsigned short)base[tid];

    unsigned int* ldst = (unsigned int*)(lidxArr + (size_t)blockIdx.x * BLK_ATOMS);
    const unsigned int* lsrc = (const unsigned int*)s_lidx;
    #pragma unroll
    for (int k = 0; k < BLK_ATOMS / 2 / 256; ++k)
        ldst[k * 256 + tid] = lsrc[k * 256 + tid];

    uint4* vdst = valArr + (size_t)blockIdx.x * BLK_ATOMS;
    #pragma unroll
    for (int k = 0; k < BLK_ATOMS / 256; ++k)
        vdst[k * 256 + tid] = s_val[k * 256 + tid];
}

// K2: accum with fused last-block merge. Block (bucket, split) accumulates its
// source-block range into a 32 KiB LDS tile, writes its partial; the LAST
// block per bucket (device-scope counter, order-independent) sums all partials
// and writes the bucket's slice of out.
__global__ void __launch_bounds__(256) vdw_accum_merge_kernel(
    const unsigned short* __restrict__ hdrArr,
    const unsigned short* __restrict__ lidxArr,
    const uint4*          __restrict__ valArr,
    float*                __restrict__ partial,
    unsigned int*         __restrict__ done,
    float*                __restrict__ out,
    int nblocks, int nsplit)
{
    __shared__ float acc[LSLOTS];
    __shared__ int   s_last;
    const int tid = threadIdx.x;
    for (int k = tid; k < LSLOTS; k += 256) acc[k] = 0.0f;
    __syncthreads();

    const int bucket = blockIdx.x / nsplit;
    const int split  = blockIdx.x % nsplit;
    const int per = (nblocks + nsplit - 1) / nsplit;
    const int b0  = split * per;
    const int b1  = (b0 + per < nblocks) ? (b0 + per) : nblocks;

    const int g    = tid >> 5;    // 8 groups of 32 lanes
    const int lane = tid & 31;

    for (int blk = b0 + g; blk < b1; blk += 8) {
        const int start = hdrArr[blk * 64 + bucket];
        const int end   = hdrArr[blk * 64 + bucket + 1];
        const unsigned short* la = lidxArr + (size_t)blk * BLK_ATOMS;
        const uint4*          va = valArr  + (size_t)blk * BLK_ATOMS;
        for (int rec = start + lane; rec < end; rec += 32) {
            const int   l = la[rec];
            const uint4 v = va[rec];
            float t;
            t = __uint_as_float(v.x << 16);          if (t != 0.0f) atomicAdd(&acc[l + 0], t);
            t = __uint_as_float(v.x & 0xffff0000u);  if (t != 0.0f) atomicAdd(&acc[l + 1], t);
            t = __uint_as_float(v.y << 16);          if (t != 0.0f) atomicAdd(&acc[l + 2], t);
            t = __uint_as_float(v.y & 0xffff0000u);  if (t != 0.0f) atomicAdd(&acc[l + 3], t);
            t = __uint_as_float(v.z << 16);          if (t != 0.0f) atomicAdd(&acc[l + 4], t);
            t = __uint_as_float(v.z & 0xffff0000u);  if (t != 0.0f) atomicAdd(&acc[l + 5], t);
            t = __uint_as_float(v.w << 16);          if (t != 0.0f) atomicAdd(&acc[l + 6], t);
            t = __uint_as_float(v.w & 0xffff0000u);  if (t != 0.0f) atomicAdd(&acc[l + 7], t);
        }
    }
    __syncthreads();

    // publish my partial
    float* dst = partial + (size_t)blockIdx.x * LSLOTS;
    for (int k = tid; k < LSLOTS; k += 256) dst[k] = acc[k];
    __threadfence();                       // release: partial visible before counter
    if (tid == 0)
        s_last = (atomicAdd(&done[bucket], 1u) == (unsigned int)(nsplit - 1));
    __syncthreads();

    if (s_last) {
        __threadfence();                   // acquire: see all partials
        const int b = bucket >> 2;         // bucket = b*4+c
        const int c = bucket & 3;
        for (int k = tid; k < LSLOTS; k += 256) {
            float s = acc[k];              // own contribution from LDS
            for (int sp = 0; sp < nsplit; ++sp) {
                if (sp == split) continue;
                s += partial[(size_t)(bucket * nsplit + sp) * LSLOTS + k];
            }
            const int bb    = k >> 12;     // k = bb*4096 + r*8 + alt
            const int inner = k & 4095;
            out[bb * OUT_HALF + b * (CDIM * RDIM * NALT) + c * 4096 + inner] = s;
        }
    }
}

// Fallback (small ws): direct global atomics into d_out.
__global__ void __launch_bounds__(256) vdw_atomic_kernel(
    const int*   __restrict__ desc,
    const int*   __restrict__ mask,
    const float* __restrict__ facc,
    const float* __restrict__ props,
    const float* __restrict__ weight,
    float*       __restrict__ out,
    int n)
{
    const int i = blockIdx.x * blockDim.x + threadIdx.x;
    if (i >= n) return;
    const float scale = (1.0f - tanhf(weight[0])) * 0.3f;
    const int4 d = reinterpret_cast<const int4*>(desc)[i];
    if (d.w == -1) return;
    const float vs = props[d.x * 8 + 0] * scale;
    const int   bb = (d.x >= 0 && d.x <= 3) ? 0 : 1;
    float* base = out + bb * OUT_HALF + (((d.y * CDIM + d.z) * RDIM + d.w) * NALT);
    const float4 f0 = reinterpret_cast<const float4*>(facc)[i * 2 + 0];
    const float4 f1 = reinterpret_cast<const float4*>(facc)[i * 2 + 1];
    const int4   m0 = reinterpret_cast<const int4*>(mask)[i * 2 + 0];
    const int4   m1 = reinterpret_cast<const int4*>(mask)[i * 2 + 1];
    if (m0.x) atomicAdd(base + 0, vs * fmaxf(f0.x, 0.0f));
    if (m0.y) atomicAdd(base + 1, vs * fmaxf(f0.y, 0.0f));
    if (m0.z) atomicAdd(base + 2, vs * fmaxf(f0.z, 0.0f));
    if (m0.w) atomicAdd(base + 3, vs * fmaxf(f0.w, 0.0f));
    if (m1.x) atomicAdd(base + 4, vs * fmaxf(f1.x, 0.0f));
    if (m1.y) atomicAdd(base + 5, vs * fmaxf(f1.y, 0.0f));
    if (m1.z) atomicAdd(base + 6, vs * fmaxf(f1.z, 0.0f));
    if (m1.w) atomicAdd(base + 7, vs * fmaxf(f1.w, 0.0f));
}

extern "C" void kernel_launch(void* const* d_in, const int* in_sizes, int n_in,
                              void* d_out, int out_size, void* d_ws, size_t ws_size,
                              hipStream_t stream)
{
    // Inputs per setup_inputs():
    // 0: coords (unused)  1: atom_description (N,4) int32
    // 2: alternativeMask (N,8) int32  3: facc (N,8) f32
    // 4: atom_Properties (500,8) f32  5: weight (1,) f32
    const int*   desc   = (const int*)d_in[1];
    const int*   mask   = (const int*)d_in[2];
    const float* facc   = (const float*)d_in[3];
    const float* props  = (const float*)d_in[4];
    const float* weight = (const float*)d_in[5];
    float*       out    = (float*)d_out;

    const int n       = in_sizes[1] / 4;
    const int nblocks = (n + BLK_ATOMS - 1) / BLK_ATOMS;

    auto align256 = [](size_t x) { return (x + 255) & ~(size_t)255; };
    const size_t off_hdr  = 0;
    const size_t off_lidx = align256(off_hdr  + (size_t)nblocks * 64 * 2);
    const size_t off_val  = align256(off_lidx + (size_t)nblocks * BLK_ATOMS * 2);
    const size_t off_part = align256(off_val  + (size_t)nblocks * BLK_ATOMS * 16);

    int nsplit = 0;
    size_t off_done = 0;
    for (int cand = 8; cand >= 1; cand >>= 1) {
        const size_t pd = align256(off_part +
            (size_t)NBUCKET * cand * LSLOTS * sizeof(float));
        if (pd + NBUCKET * sizeof(unsigned int) <= ws_size) {
            nsplit = cand; off_done = pd; break;
        }
    }

    if (nsplit >= 1) {
        char* ws = (char*)d_ws;
        unsigned short* hdrArr  = (unsigned short*)(ws + off_hdr);
        unsigned short* lidxArr = (unsigned short*)(ws + off_lidx);
        uint4*          valArr  = (uint4*)(ws + off_val);
        float*          part    = (float*)(ws + off_part);
        unsigned int*   done    = (unsigned int*)(ws + off_done);

        hipMemsetAsync(done, 0, NBUCKET * sizeof(unsigned int), stream);

        vdw_fused_kernel<<<nblocks, 256, 0, stream>>>(
            (const int4*)desc, (const int4*)mask, (const float4*)facc,
            props, weight, hdrArr, lidxArr, valArr, n);

        vdw_accum_merge_kernel<<<NBUCKET * nsplit, 256, 0, stream>>>(
            hdrArr, lidxArr, valArr, part, done, out, nblocks, nsplit);
    } else {
        hipMemsetAsync(d_out, 0, (size_t)out_size * sizeof(float), stream);
        vdw_atomic_kernel<<<(n + 255) / 256, 256, 0, stream>>>(
            desc, mask, facc, props, weight, out, n);
    }
}

// Round 12
// 89.852 us; speedup vs baseline: 2.0134x; 2.0134x over previous
//
#include <hip/hip_runtime.h>
#include <hip/hip_bf16.h>
#include <math.h>

// Problem constants (from the reference)
#define NALT      8
#define BDIM      8
#define CDIM      4
#define RDIM      512
#define OUT_HALF  (BDIM * CDIM * RDIM * NALT)   // 131072 floats
#define OUT_TOTAL (2 * OUT_HALF)                // 262144 floats [MC | SC]

#define NBUCKET   32          // bucket = b*4+c
#define BLK_ATOMS 1024        // atoms per block (256 thr x AITER)
#define AITER     4
#define NWAVE     4           // 256 threads / 64
#define LSLOTS    8192        // accum LDS tile: bb(2)*r(512)*alt(8) f32 = 32 KiB

// ws layout (runtime offsets, 256B-aligned):
//   hdr  u16 [nblocks][64]   (0..32 = exclusive bucket offsets in block)
//   lidx u16 [nblocks][1024]
//   vals uint4[nblocks][1024]
//   partial f32 [NBUCKET*nsplit][LSLOTS]

__device__ __forceinline__ unsigned int pack_bf16_2(float a, float b) {
    unsigned int ua = __float_as_uint(a);
    unsigned int ub = __float_as_uint(b);
    ua = (ua + 0x7fffu + ((ua >> 16) & 1u)) >> 16;   // round-to-nearest-even
    ub = (ub + 0x7fffu + ((ub >> 16) & 1u)) >> 16;
    return ua | (ub << 16);
}

// K1: fused count+scan+compact (R11 front-end, proven ~30us).
// One desc read. All global loads issue up front; values computed (f/m
// consumed) BEFORE the first barrier so the barrier-drain waits on an
// already-consumed stream. Records staged in LDS (scatter absorbed), then
// block-major coalesced copy-out (zero write inflation, R8/R10 evidence).
__global__ void __launch_bounds__(256) vdw_fused_kernel(
    const int4*   __restrict__ desc,
    const int4*   __restrict__ mask,
    const float4* __restrict__ facc,
    const float*  __restrict__ props,
    const float*  __restrict__ weight,
    unsigned short* __restrict__ hdrArr,   // [nblocks][64]
    unsigned short* __restrict__ lidxArr,  // [nblocks][1024]
    uint4*        __restrict__ valArr,     // [nblocks][1024]
    int n)
{
    __shared__ unsigned int   cw[NWAVE][NBUCKET];
    __shared__ unsigned int   tot[NBUCKET];
    __shared__ unsigned int   base[NBUCKET + 1];
    __shared__ unsigned short s_lidx[BLK_ATOMS];
    __shared__ uint4          s_val[BLK_ATOMS];

    const int tid  = threadIdx.x;
    const int w    = tid >> 6;
    const int lane = tid & 63;
    if (lane < NBUCKET) cw[w][lane] = 0;   // wave-lockstep, ordered before this wave's atomics

    // ---- issue ALL global loads up front (max MLP) ----
    const int a0 = blockIdx.x * BLK_ATOMS;
    int4   d_[AITER];
    float4 f0_[AITER], f1_[AITER];
    int4   m0_[AITER], m1_[AITER];
    bool   ok[AITER];
    #pragma unroll
    for (int it = 0; it < AITER; ++it) {
        const int a  = a0 + it * 256 + tid;
        ok[it] = (a < n);
        const int aa = ok[it] ? a : (n - 1);
        d_[it]  = desc[aa];
        f0_[it] = facc[aa * 2 + 0];
        f1_[it] = facc[aa * 2 + 1];
        m0_[it] = mask[aa * 2 + 0];
        m1_[it] = mask[aa * 2 + 1];
    }
    const float scale = (1.0f - tanhf(weight[0])) * 0.3f;

    // ---- histogram (consumes desc only; f/m still in flight) ----
    int bkt[AITER];
    int lidx[AITER];
    #pragma unroll
    for (int it = 0; it < AITER; ++it) {
        const int4 d = d_[it];
        bkt[it] = -1;
        if (ok[it] && d.w != -1) {
            bkt[it]  = d.y * CDIM + d.z;
            lidx[it] = ((d.x < 4) ? 0 : 4096) + d.w * 8;
            atomicAdd(&cw[w][bkt[it]], 1u);
        }
    }

    // ---- compute packed values (consumes f/m + props gather) ----
    uint4 rv[AITER];
    #pragma unroll
    for (int it = 0; it < AITER; ++it) {
        if (bkt[it] < 0) continue;
        const float vs = props[d_[it].x * 8] * scale;
        const float4 f0 = f0_[it], f1 = f1_[it];
        const int4   m0 = m0_[it], m1 = m1_[it];
        const float v0 = m0.x ? vs * fmaxf(f0.x, 0.0f) : 0.0f;
        const float v1 = m0.y ? vs * fmaxf(f0.y, 0.0f) : 0.0f;
        const float v2 = m0.z ? vs * fmaxf(f0.z, 0.0f) : 0.0f;
        const float v3 = m0.w ? vs * fmaxf(f0.w, 0.0f) : 0.0f;
        const float v4 = m1.x ? vs * fmaxf(f1.x, 0.0f) : 0.0f;
        const float v5 = m1.y ? vs * fmaxf(f1.y, 0.0f) : 0.0f;
        const float v6 = m1.z ? vs * fmaxf(f1.z, 0.0f) : 0.0f;
        const float v7 = m1.w ? vs * fmaxf(f1.w, 0.0f) : 0.0f;
        rv[it] = make_uint4(pack_bf16_2(v0, v1), pack_bf16_2(v2, v3),
                            pack_bf16_2(v4, v5), pack_bf16_2(v6, v7));
    }
    __syncthreads();   // b1: stream fully consumed by now

    // ---- in-block scan: per-wave prefixes + bucket bases ----
    if (tid < NBUCKET) {
        unsigned int s = 0;
        #pragma unroll
        for (int ww = 0; ww < NWAVE; ++ww) {
            const unsigned int c = cw[ww][tid];
            cw[ww][tid] = s;           // per-wave start offset within bucket
            s += c;
        }
        tot[tid] = s;
    }
    __syncthreads();   // b2
    if (tid == 0) {
        unsigned int run = 0;
        #pragma unroll
        for (int j = 0; j < NBUCKET; ++j) { base[j] = run; run += tot[j]; }
        base[NBUCKET] = run;
    }
    __syncthreads();   // b3

    // ---- stage into LDS at bucket-grouped positions ----
    #pragma unroll
    for (int it = 0; it < AITER; ++it) {
        if (bkt[it] < 0) continue;
        const unsigned int pos = base[bkt[it]] + atomicAdd(&cw[w][bkt[it]], 1u);
        s_lidx[pos] = (unsigned short)lidx[it];
        s_val[pos]  = rv[it];
    }
    __syncthreads();   // b4 (LDS-only)

    // ---- coalesced block-major copy-out ----
    if (tid <= NBUCKET)
        hdrArr[blockIdx.x * 64 + tid] = (unsigned short)base[tid];

    unsigned int* ldst = (unsigned int*)(lidxArr + (size_t)blockIdx.x * BLK_ATOMS);
    const unsigned int* lsrc = (const unsigned int*)s_lidx;
    #pragma unroll
    for (int k = 0; k < BLK_ATOMS / 2 / 256; ++k)
        ldst[k * 256 + tid] = lsrc[k * 256 + tid];

    uint4* vdst = valArr + (size_t)blockIdx.x * BLK_ATOMS;
    #pragma unroll
    for (int k = 0; k < BLK_ATOMS / 256; ++k)
        vdst[k * 256 + tid] = s_val[k * 256 + tid];
}

// K2: accum (R9 back-end). Block (bucket, split) walks its source-block
// range's bucket runs (contiguous bursts) into a 32 KiB LDS tile; writes
// dense partial. No fences, no cross-XCD games.
__global__ void __launch_bounds__(256) vdw_accum_kernel(
    const unsigned short* __restrict__ hdrArr,
    const unsigned short* __restrict__ lidxArr,
    const uint4*          __restrict__ valArr,
    float*                __restrict__ partial,
    int nblocks, int nsplit)
{
    __shared__ float acc[LSLOTS];
    const int tid = threadIdx.x;
    for (int k = tid; k < LSLOTS; k += 256) acc[k] = 0.0f;
    __syncthreads();

    const int bucket = blockIdx.x / nsplit;
    const int split  = blockIdx.x % nsplit;
    const int per = (nblocks + nsplit - 1) / nsplit;
    const int b0  = split * per;
    const int b1  = (b0 + per < nblocks) ? (b0 + per) : nblocks;

    const int g    = tid >> 5;    // 8 groups of 32 lanes
    const int lane = tid & 31;

    for (int blk = b0 + g; blk < b1; blk += 8) {
        const int start = hdrArr[blk * 64 + bucket];
        const int end   = hdrArr[blk * 64 + bucket + 1];
        const unsigned short* la = lidxArr + (size_t)blk * BLK_ATOMS;
        const uint4*          va = valArr  + (size_t)blk * BLK_ATOMS;
        for (int rec = start + lane; rec < end; rec += 32) {
            const int   l = la[rec];
            const uint4 v = va[rec];
            float t;
            t = __uint_as_float(v.x << 16);          if (t != 0.0f) atomicAdd(&acc[l + 0], t);
            t = __uint_as_float(v.x & 0xffff0000u);  if (t != 0.0f) atomicAdd(&acc[l + 1], t);
            t = __uint_as_float(v.y << 16);          if (t != 0.0f) atomicAdd(&acc[l + 2], t);
            t = __uint_as_float(v.y & 0xffff0000u);  if (t != 0.0f) atomicAdd(&acc[l + 3], t);
            t = __uint_as_float(v.z << 16);          if (t != 0.0f) atomicAdd(&acc[l + 4], t);
            t = __uint_as_float(v.z & 0xffff0000u);  if (t != 0.0f) atomicAdd(&acc[l + 5], t);
            t = __uint_as_float(v.w << 16);          if (t != 0.0f) atomicAdd(&acc[l + 6], t);
            t = __uint_as_float(v.w & 0xffff0000u);  if (t != 0.0f) atomicAdd(&acc[l + 7], t);
        }
    }
    __syncthreads();

    float* dst = partial + (size_t)blockIdx.x * LSLOTS;
    for (int k = tid; k < LSLOTS; k += 256) dst[k] = acc[k];
}

// K3: merge. out[idx] = sum over splits of matching partial. Writes every
// output element (no d_out memset needed).
__global__ void __launch_bounds__(256) vdw_merge_kernel(
    const float* __restrict__ partial,
    float*       __restrict__ out,
    int nsplit)
{
    const int idx = blockIdx.x * 256 + threadIdx.x;
    if (idx >= OUT_TOTAL) return;
    // idx = (((bb*8+b)*4+c)*512 + r)*8 + alt
    const int bb     = idx >> 17;
    const int b      = (idx >> 14) & 7;
    const int c      = (idx >> 12) & 3;
    const int lidx   = bb * 4096 + (idx & 4095);   // r*8+alt
    const int bucket = b * CDIM + c;
    const float* p = partial + ((size_t)bucket * nsplit) * LSLOTS + lidx;
    float s = 0.0f;
    for (int sp = 0; sp < nsplit; ++sp)
        s += p[(size_t)sp * LSLOTS];
    out[idx] = s;
}

// Fallback (small ws): direct global atomics into d_out.
__global__ void __launch_bounds__(256) vdw_atomic_kernel(
    const int*   __restrict__ desc,
    const int*   __restrict__ mask,
    const float* __restrict__ facc,
    const float* __restrict__ props,
    const float* __restrict__ weight,
    float*       __restrict__ out,
    int n)
{
    const int i = blockIdx.x * blockDim.x + threadIdx.x;
    if (i >= n) return;
    const float scale = (1.0f - tanhf(weight[0])) * 0.3f;
    const int4 d = reinterpret_cast<const int4*>(desc)[i];
    if (d.w == -1) return;
    const float vs = props[d.x * 8 + 0] * scale;
    const int   bb = (d.x >= 0 && d.x <= 3) ? 0 : 1;
    float* base = out + bb * OUT_HALF + (((d.y * CDIM + d.z) * RDIM + d.w) * NALT);
    const float4 f0 = reinterpret_cast<const float4*>(facc)[i * 2 + 0];
    const float4 f1 = reinterpret_cast<const float4*>(facc)[i * 2 + 1];
    const int4   m0 = reinterpret_cast<const int4*>(mask)[i * 2 + 0];
    const int4   m1 = reinterpret_cast<const int4*>(mask)[i * 2 + 1];
    if (m0.x) atomicAdd(base + 0, vs * fmaxf(f0.x, 0.0f));
    if (m0.y) atomicAdd(base + 1, vs * fmaxf(f0.y, 0.0f));
    if (m0.z) atomicAdd(base + 2, vs * fmaxf(f0.z, 0.0f));
    if (m0.w) atomicAdd(base + 3, vs * fmaxf(f0.w, 0.0f));
    if (m1.x) atomicAdd(base + 4, vs * fmaxf(f1.x, 0.0f));
    if (m1.y) atomicAdd(base + 5, vs * fmaxf(f1.y, 0.0f));
    if (m1.z) atomicAdd(base + 6, vs * fmaxf(f1.z, 0.0f));
    if (m1.w) atomicAdd(base + 7, vs * fmaxf(f1.w, 0.0f));
}

extern "C" void kernel_launch(void* const* d_in, const int* in_sizes, int n_in,
                              void* d_out, int out_size, void* d_ws, size_t ws_size,
                              hipStream_t stream)
{
    // Inputs per setup_inputs():
    // 0: coords (unused)  1: atom_description (N,4) int32
    // 2: alternativeMask (N,8) int32  3: facc (N,8) f32
    // 4: atom_Properties (500,8) f32  5: weight (1,) f32
    const int*   desc   = (const int*)d_in[1];
    const int*   mask   = (const int*)d_in[2];
    const float* facc   = (const float*)d_in[3];
    const float* props  = (const float*)d_in[4];
    const float* weight = (const float*)d_in[5];
    float*       out    = (float*)d_out;

    const int n       = in_sizes[1] / 4;
    const int nblocks = (n + BLK_ATOMS - 1) / BLK_ATOMS;

    auto align256 = [](size_t x) { return (x + 255) & ~(size_t)255; };
    const size_t off_hdr  = 0;
    const size_t off_lidx = align256(off_hdr  + (size_t)nblocks * 64 * 2);
    const size_t off_val  = align256(off_lidx + (size_t)nblocks * BLK_ATOMS * 2);
    const size_t off_part = align256(off_val  + (size_t)nblocks * BLK_ATOMS * 16);

    int nsplit = 0;
    for (int cand = 16; cand >= 1; cand >>= 1) {
        const size_t need = off_part +
            (size_t)NBUCKET * cand * LSLOTS * sizeof(float);
        if (need <= ws_size) { nsplit = cand; break; }
    }

    if (nsplit >= 1) {
        char* ws = (char*)d_ws;
        unsigned short* hdrArr  = (unsigned short*)(ws + off_hdr);
        unsigned short* lidxArr = (unsigned short*)(ws + off_lidx);
        uint4*          valArr  = (uint4*)(ws + off_val);
        float*          part    = (float*)(ws + off_part);

        vdw_fused_kernel<<<nblocks, 256, 0, stream>>>(
            (const int4*)desc, (const int4*)mask, (const float4*)facc,
            props, weight, hdrArr, lidxArr, valArr, n);

        vdw_accum_kernel<<<NBUCKET * nsplit, 256, 0, stream>>>(
            hdrArr, lidxArr, valArr, part, nblocks, nsplit);

        vdw_merge_kernel<<<(OUT_TOTAL + 255) / 256, 256, 0, stream>>>(
            part, out, nsplit);
    } else {
        hipMemsetAsync(d_out, 0, (size_t)out_size * sizeof(float), stream);
        vdw_atomic_kernel<<<(n + 255) / 256, 256, 0, stream>>>(
            desc, mask, facc, props, weight, out, n);
    }
}

// Round 13
// 87.526 us; speedup vs baseline: 2.0669x; 1.0266x over previous
//
#include <hip/hip_runtime.h>
#include <hip/hip_bf16.h>
#include <math.h>

// Problem constants (from the reference)
#define NALT      8
#define BDIM      8
#define CDIM      4
#define RDIM      512
#define OUT_HALF  (BDIM * CDIM * RDIM * NALT)   // 131072 floats
#define OUT_TOTAL (2 * OUT_HALF)                // 262144 floats [MC | SC]

#define NBUCKET   32          // bucket = b*4+c
#define BLK_ATOMS 512         // atoms per block (256 thr x AITER=2)
#define AITER     2
#define NWAVE     4           // 256 threads / 64
#define LSLOTS    8192        // accum LDS tile: bb(2)*r(512)*alt(8) f32 = 32 KiB

// ws layout (runtime offsets, 256B-aligned):
//   hdr  u16 [nblocks][64]   (0..32 = exclusive bucket offsets in block)
//   lidx u16 [nblocks][512]
//   vals uint4[nblocks][512]
//   partial f32 [NBUCKET*nsplit][LSLOTS]

__device__ __forceinline__ unsigned int pack_bf16_2(float a, float b) {
    unsigned int ua = __float_as_uint(a);
    unsigned int ub = __float_as_uint(b);
    ua = (ua + 0x7fffu + ((ua >> 16) & 1u)) >> 16;   // round-to-nearest-even
    ub = (ub + 0x7fffu + ((ub >> 16) & 1u)) >> 16;
    return ua | (ub << 16);
}

// K1: fused count+scan+compact, 512-atom blocks so the 10 16B-loads/thread
// (40 VGPR payload) genuinely issue before first use (R12: at AITER=4 the
// compiler serialized the stream -- VGPR_Count 52 < the 80 needed).
__global__ void __launch_bounds__(256) vdw_fused_kernel(
    const int4*   __restrict__ desc,
    const int4*   __restrict__ mask,
    const float4* __restrict__ facc,
    const float*  __restrict__ props,
    const float*  __restrict__ weight,
    unsigned short* __restrict__ hdrArr,   // [nblocks][64]
    unsigned short* __restrict__ lidxArr,  // [nblocks][512]
    uint4*        __restrict__ valArr,     // [nblocks][512]
    int n)
{
    __shared__ unsigned int   cw[NWAVE][NBUCKET];
    __shared__ unsigned int   base[NBUCKET + 1];
    __shared__ unsigned short s_lidx[BLK_ATOMS];
    __shared__ uint4          s_val[BLK_ATOMS];

    const int tid  = threadIdx.x;
    const int w    = tid >> 6;
    const int lane = tid & 63;
    if (lane < NBUCKET) cw[w][lane] = 0;   // wave-lockstep, ordered before this wave's atomics

    // ---- issue ALL global loads up front (fits in VGPRs now) ----
    const int a0 = blockIdx.x * BLK_ATOMS;
    int4   d_[AITER];
    float4 f0_[AITER], f1_[AITER];
    int4   m0_[AITER], m1_[AITER];
    bool   ok[AITER];
    #pragma unroll
    for (int it = 0; it < AITER; ++it) {
        const int a  = a0 + it * 256 + tid;
        ok[it] = (a < n);
        const int aa = ok[it] ? a : (n - 1);
        d_[it]  = desc[aa];
        f0_[it] = facc[aa * 2 + 0];
        f1_[it] = facc[aa * 2 + 1];
        m0_[it] = mask[aa * 2 + 0];
        m1_[it] = mask[aa * 2 + 1];
    }
    const float scale = (1.0f - tanhf(weight[0])) * 0.3f;

    // ---- histogram (consumes desc only; f/m still in flight) ----
    int bkt[AITER];
    int lidx[AITER];
    #pragma unroll
    for (int it = 0; it < AITER; ++it) {
        const int4 d = d_[it];
        bkt[it] = -1;
        if (ok[it] && d.w != -1) {
            bkt[it]  = d.y * CDIM + d.z;
            lidx[it] = ((d.x < 4) ? 0 : 4096) + d.w * 8;
            atomicAdd(&cw[w][bkt[it]], 1u);
        }
    }

    // ---- compute packed values (consumes f/m + props gather) ----
    uint4 rv[AITER];
    #pragma unroll
    for (int it = 0; it < AITER; ++it) {
        if (bkt[it] < 0) continue;
        const float vs = props[d_[it].x * 8] * scale;
        const float4 f0 = f0_[it], f1 = f1_[it];
        const int4   m0 = m0_[it], m1 = m1_[it];
        const float v0 = m0.x ? vs * fmaxf(f0.x, 0.0f) : 0.0f;
        const float v1 = m0.y ? vs * fmaxf(f0.y, 0.0f) : 0.0f;
        const float v2 = m0.z ? vs * fmaxf(f0.z, 0.0f) : 0.0f;
        const float v3 = m0.w ? vs * fmaxf(f0.w, 0.0f) : 0.0f;
        const float v4 = m1.x ? vs * fmaxf(f1.x, 0.0f) : 0.0f;
        const float v5 = m1.y ? vs * fmaxf(f1.y, 0.0f) : 0.0f;
        const float v6 = m1.z ? vs * fmaxf(f1.z, 0.0f) : 0.0f;
        const float v7 = m1.w ? vs * fmaxf(f1.w, 0.0f) : 0.0f;
        rv[it] = make_uint4(pack_bf16_2(v0, v1), pack_bf16_2(v2, v3),
                            pack_bf16_2(v4, v5), pack_bf16_2(v6, v7));
    }
    __syncthreads();   // b1: stream fully consumed by now

    // ---- in-block scan: per-wave prefixes + lane-parallel bucket-base scan ----
    if (tid < NBUCKET) {
        unsigned int s = 0;
        #pragma unroll
        for (int ww = 0; ww < NWAVE; ++ww) {
            const unsigned int c = cw[ww][tid];
            cw[ww][tid] = s;           // per-wave start offset within bucket
            s += c;
        }
        // inclusive scan across the 32 buckets (lanes 0..31 of wave 0)
        unsigned int incl = s;
        #pragma unroll
        for (int off = 1; off < NBUCKET; off <<= 1) {
            const unsigned int t = __shfl_up(incl, off, NBUCKET);
            if (tid >= off) incl += t;
        }
        base[tid] = incl - s;
        if (tid == NBUCKET - 1) base[NBUCKET] = incl;
    }
    __syncthreads();   // b2

    // ---- stage into LDS at bucket-grouped positions ----
    #pragma unroll
    for (int it = 0; it < AITER; ++it) {
        if (bkt[it] < 0) continue;
        const unsigned int pos = base[bkt[it]] + atomicAdd(&cw[w][bkt[it]], 1u);
        s_lidx[pos] = (unsigned short)lidx[it];
        s_val[pos]  = rv[it];
    }
    __syncthreads();   // b3 (LDS-only)

    // ---- coalesced block-major copy-out ----
    if (tid <= NBUCKET)
        hdrArr[blockIdx.x * 64 + tid] = (unsigned short)base[tid];

    unsigned int* ldst = (unsigned int*)(lidxArr + (size_t)blockIdx.x * BLK_ATOMS);
    const unsigned int* lsrc = (const unsigned int*)s_lidx;
    #pragma unroll
    for (int k = 0; k < BLK_ATOMS / 2 / 256; ++k)
        ldst[k * 256 + tid] = lsrc[k * 256 + tid];

    uint4* vdst = valArr + (size_t)blockIdx.x * BLK_ATOMS;
    #pragma unroll
    for (int k = 0; k < BLK_ATOMS / 256; ++k)
        vdst[k * 256 + tid] = s_val[k * 256 + tid];
}

// K2: accum. Block (bucket, split) walks its source-block range's bucket runs
// (contiguous bursts) into a 32 KiB LDS tile; writes dense partial.
__global__ void __launch_bounds__(256) vdw_accum_kernel(
    const unsigned short* __restrict__ hdrArr,
    const unsigned short* __restrict__ lidxArr,
    const uint4*          __restrict__ valArr,
    float*                __restrict__ partial,
    int nblocks, int nsplit)
{
    __shared__ float acc[LSLOTS];
    const int tid = threadIdx.x;
    for (int k = tid; k < LSLOTS; k += 256) acc[k] = 0.0f;
    __syncthreads();

    const int bucket = blockIdx.x / nsplit;
    const int split  = blockIdx.x % nsplit;
    const int per = (nblocks + nsplit - 1) / nsplit;
    const int b0  = split * per;
    const int b1  = (b0 + per < nblocks) ? (b0 + per) : nblocks;

    const int g    = tid >> 5;    // 8 groups of 32 lanes
    const int lane = tid & 31;

    for (int blk = b0 + g; blk < b1; blk += 8) {
        const int start = hdrArr[blk * 64 + bucket];
        const int end   = hdrArr[blk * 64 + bucket + 1];
        const unsigned short* la = lidxArr + (size_t)blk * BLK_ATOMS;
        const uint4*          va = valArr  + (size_t)blk * BLK_ATOMS;
        for (int rec = start + lane; rec < end; rec += 32) {
            const int   l = la[rec];
            const uint4 v = va[rec];
            float t;
            t = __uint_as_float(v.x << 16);          if (t != 0.0f) atomicAdd(&acc[l + 0], t);
            t = __uint_as_float(v.x & 0xffff0000u);  if (t != 0.0f) atomicAdd(&acc[l + 1], t);
            t = __uint_as_float(v.y << 16);          if (t != 0.0f) atomicAdd(&acc[l + 2], t);
            t = __uint_as_float(v.y & 0xffff0000u);  if (t != 0.0f) atomicAdd(&acc[l + 3], t);
            t = __uint_as_float(v.z << 16);          if (t != 0.0f) atomicAdd(&acc[l + 4], t);
            t = __uint_as_float(v.z & 0xffff0000u);  if (t != 0.0f) atomicAdd(&acc[l + 5], t);
            t = __uint_as_float(v.w << 16);          if (t != 0.0f) atomicAdd(&acc[l + 6], t);
            t = __uint_as_float(v.w & 0xffff0000u);  if (t != 0.0f) atomicAdd(&acc[l + 7], t);
        }
    }
    __syncthreads();

    float* dst = partial + (size_t)blockIdx.x * LSLOTS;
    for (int k = tid; k < LSLOTS; k += 256) dst[k] = acc[k];
}

// K3: merge. out[idx] = sum over splits of matching partial. Writes every
// output element (no d_out memset needed).
__global__ void __launch_bounds__(256) vdw_merge_kernel(
    const float* __restrict__ partial,
    float*       __restrict__ out,
    int nsplit)
{
    const int idx = blockIdx.x * 256 + threadIdx.x;
    if (idx >= OUT_TOTAL) return;
    // idx = (((bb*8+b)*4+c)*512 + r)*8 + alt
    const int bb     = idx >> 17;
    const int b      = (idx >> 14) & 7;
    const int c      = (idx >> 12) & 3;
    const int lidx   = bb * 4096 + (idx & 4095);   // r*8+alt
    const int bucket = b * CDIM + c;
    const float* p = partial + ((size_t)bucket * nsplit) * LSLOTS + lidx;
    float s = 0.0f;
    for (int sp = 0; sp < nsplit; ++sp)
        s += p[(size_t)sp * LSLOTS];
    out[idx] = s;
}

// Fallback (small ws): direct global atomics into d_out.
__global__ void __launch_bounds__(256) vdw_atomic_kernel(
    const int*   __restrict__ desc,
    const int*   __restrict__ mask,
    const float* __restrict__ facc,
    const float* __restrict__ props,
    const float* __restrict__ weight,
    float*       __restrict__ out,
    int n)
{
    const int i = blockIdx.x * blockDim.x + threadIdx.x;
    if (i >= n) return;
    const float scale = (1.0f - tanhf(weight[0])) * 0.3f;
    const int4 d = reinterpret_cast<const int4*>(desc)[i];
    if (d.w == -1) return;
    const float vs = props[d.x * 8 + 0] * scale;
    const int   bb = (d.x >= 0 && d.x <= 3) ? 0 : 1;
    float* base = out + bb * OUT_HALF + (((d.y * CDIM + d.z) * RDIM + d.w) * NALT);
    const float4 f0 = reinterpret_cast<const float4*>(facc)[i * 2 + 0];
    const float4 f1 = reinterpret_cast<const float4*>(facc)[i * 2 + 1];
    const int4   m0 = reinterpret_cast<const int4*>(mask)[i * 2 + 0];
    const int4   m1 = reinterpret_cast<const int4*>(mask)[i * 2 + 1];
    if (m0.x) atomicAdd(base + 0, vs * fmaxf(f0.x, 0.0f));
    if (m0.y) atomicAdd(base + 1, vs * fmaxf(f0.y, 0.0f));
    if (m0.z) atomicAdd(base + 2, vs * fmaxf(f0.z, 0.0f));
    if (m0.w) atomicAdd(base + 3, vs * fmaxf(f0.w, 0.0f));
    if (m1.x) atomicAdd(base + 4, vs * fmaxf(f1.x, 0.0f));
    if (m1.y) atomicAdd(base + 5, vs * fmaxf(f1.y, 0.0f));
    if (m1.z) atomicAdd(base + 6, vs * fmaxf(f1.z, 0.0f));
    if (m1.w) atomicAdd(base + 7, vs * fmaxf(f1.w, 0.0f));
}

extern "C" void kernel_launch(void* const* d_in, const int* in_sizes, int n_in,
                              void* d_out, int out_size, void* d_ws, size_t ws_size,
                              hipStream_t stream)
{
    // Inputs per setup_inputs():
    // 0: coords (unused)  1: atom_description (N,4) int32
    // 2: alternativeMask (N,8) int32  3: facc (N,8) f32
    // 4: atom_Properties (500,8) f32  5: weight (1,) f32
    const int*   desc   = (const int*)d_in[1];
    const int*   mask   = (const int*)d_in[2];
    const float* facc   = (const float*)d_in[3];
    const float* props  = (const float*)d_in[4];
    const float* weight = (const float*)d_in[5];
    float*       out    = (float*)d_out;

    const int n       = in_sizes[1] / 4;
    const int nblocks = (n + BLK_ATOMS - 1) / BLK_ATOMS;

    auto align256 = [](size_t x) { return (x + 255) & ~(size_t)255; };
    const size_t off_hdr  = 0;
    const size_t off_lidx = align256(off_hdr  + (size_t)nblocks * 64 * 2);
    const size_t off_val  = align256(off_lidx + (size_t)nblocks * BLK_ATOMS * 2);
    const size_t off_part = align256(off_val  + (size_t)nblocks * BLK_ATOMS * 16);

    int nsplit = 0;
    for (int cand = 16; cand >= 1; cand >>= 1) {
        const size_t need = off_part +
            (size_t)NBUCKET * cand * LSLOTS * sizeof(float);
        if (need <= ws_size) { nsplit = cand; break; }
    }

    if (nsplit >= 1) {
        char* ws = (char*)d_ws;
        unsigned short* hdrArr  = (unsigned short*)(ws + off_hdr);
        unsigned short* lidxArr = (unsigned short*)(ws + off_lidx);
        uint4*          valArr  = (uint4*)(ws + off_val);
        float*          part    = (float*)(ws + off_part);

        vdw_fused_kernel<<<nblocks, 256, 0, stream>>>(
            (const int4*)desc, (const int4*)mask, (const float4*)facc,
            props, weight, hdrArr, lidxArr, valArr, n);

        vdw_accum_kernel<<<NBUCKET * nsplit, 256, 0, stream>>>(
            hdrArr, lidxArr, valArr, part, nblocks, nsplit);

        vdw_merge_kernel<<<(OUT_TOTAL + 255) / 256, 256, 0, stream>>>(
            part, out, nsplit);
    } else {
        hipMemsetAsync(d_out, 0, (size_t)out_size * sizeof(float), stream);
        vdw_atomic_kernel<<<(n + 255) / 256, 256, 0, stream>>>(
            desc, mask, facc, props, weight, out, n);
    }
}

// Round 14
// 87.382 us; speedup vs baseline: 2.0703x; 1.0016x over previous
//
#include <hip/hip_runtime.h>
#include <hip/hip_bf16.h>
#include <math.h>

// Problem constants (from the reference)
#define NALT      8
#define BDIM      8
#define CDIM      4
#define RDIM      512
#define OUT_HALF  (BDIM * CDIM * RDIM * NALT)   // 131072 floats
#define OUT_TOTAL (2 * OUT_HALF)                // 262144 floats [MC | SC]

#define NBUCKET   32          // bucket = b*4+c
#define BLK_ATOMS 512         // atoms per block (256 thr x AITER=2)
#define AITER     2
#define NWAVE     4           // 256 threads / 64
#define LSLOTS    8192        // accum LDS tile: bb(2)*r(512)*alt(8) f32 = 32 KiB

// ws layout (runtime offsets, 256B-aligned):
//   hdr  u16 [nblocks][64]   (0..32 = exclusive bucket offsets in block)
//   lidx u16 [nblocks][512]
//   vals uint4[nblocks][512]
//   partial f32 [NBUCKET*nsplit][LSLOTS]

// 16B global -> LDS async DMA (never auto-emitted by hipcc).
// LDS dest must be wave-uniform; HW adds lane*16.
#define DMA16(gp, lp) __builtin_amdgcn_global_load_lds(                        \
    (const __attribute__((address_space(1))) unsigned int*)(gp),               \
    (__attribute__((address_space(3))) unsigned int*)(lp), 16, 0, 0)

__device__ __forceinline__ unsigned int pack_bf16_2(float a, float b) {
    unsigned int ua = __float_as_uint(a);
    unsigned int ub = __float_as_uint(b);
    ua = (ua + 0x7fffu + ((ua >> 16) & 1u)) >> 16;   // round-to-nearest-even
    ub = (ub + 0x7fffu + ((ub >> 16) & 1u)) >> 16;
    return ua | (ub << 16);
}

// K1: fused count+scan+compact with DMA-staged facc/mask.
// DMAs issue at kernel start (async, no VGPR cost); desc goes to registers
// for the histogram; barrier b1 drains the DMA queue (which streamed during
// the hist phase); compute+stage read f/m from LDS. Removes the
// compiler-controlled register-prefetch that R12/R13 proved unreliable.
__global__ void __launch_bounds__(256) vdw_fused_kernel(
    const int4*   __restrict__ desc,
    const int4*   __restrict__ mask,
    const float4* __restrict__ facc,
    const float*  __restrict__ props,
    const float*  __restrict__ weight,
    unsigned short* __restrict__ hdrArr,   // [nblocks][64]
    unsigned short* __restrict__ lidxArr,  // [nblocks][512]
    uint4*        __restrict__ valArr,     // [nblocks][512]
    int n)
{
    // s_fm: [chunk = wave*AITER+it][4 streams f0,f1,m0,m1][64 lanes][16B]
    __shared__ __align__(16) char s_fm[NWAVE * AITER * 4 * 64 * 16];  // 32 KiB
    __shared__ unsigned int   cw[NWAVE][NBUCKET];
    __shared__ unsigned int   base[NBUCKET + 1];
    __shared__ unsigned short s_lidx[BLK_ATOMS];
    __shared__ uint4          s_val[BLK_ATOMS];

    const int tid  = threadIdx.x;
    const int w    = tid >> 6;
    const int lane = tid & 63;
    if (lane < NBUCKET) cw[w][lane] = 0;   // wave-lockstep, ordered before this wave's atomics

    const int a0 = blockIdx.x * BLK_ATOMS;

    // ---- issue async DMAs for facc/mask + register loads for desc ----
    int4 d_[AITER];
    bool ok[AITER];
    #pragma unroll
    for (int it = 0; it < AITER; ++it) {
        const int a  = a0 + it * 256 + tid;
        ok[it] = (a < n);
        const int aa = ok[it] ? a : (n - 1);
        const int c8 = w * AITER + it;          // wave-uniform chunk id
        const float4* gf = facc + (size_t)aa * 2;
        const int4*   gm = mask + (size_t)aa * 2;
        DMA16(gf,     &s_fm[(c8 * 4 + 0) * 1024]);
        DMA16(gf + 1, &s_fm[(c8 * 4 + 1) * 1024]);
        DMA16(gm,     &s_fm[(c8 * 4 + 2) * 1024]);
        DMA16(gm + 1, &s_fm[(c8 * 4 + 3) * 1024]);
        d_[it] = desc[aa];
    }
    const float scale = (1.0f - tanhf(weight[0])) * 0.3f;

    // ---- histogram (desc only; DMAs stream meanwhile) ----
    int bkt[AITER];
    int lidx[AITER];
    #pragma unroll
    for (int it = 0; it < AITER; ++it) {
        const int4 d = d_[it];
        bkt[it] = -1;
        if (ok[it] && d.w != -1) {
            bkt[it]  = d.y * CDIM + d.z;
            lidx[it] = ((d.x < 4) ? 0 : 4096) + d.w * 8;
            atomicAdd(&cw[w][bkt[it]], 1u);
        }
    }
    __syncthreads();   // b1: drains DMA queue (covered by hist phase)

    // ---- in-block scan: per-wave prefixes + lane-parallel bucket-base scan ----
    if (tid < NBUCKET) {
        unsigned int s = 0;
        #pragma unroll
        for (int ww = 0; ww < NWAVE; ++ww) {
            const unsigned int c = cw[ww][tid];
            cw[ww][tid] = s;           // per-wave start offset within bucket
            s += c;
        }
        unsigned int incl = s;
        #pragma unroll
        for (int off = 1; off < NBUCKET; off <<= 1) {
            const unsigned int t = __shfl_up(incl, off, NBUCKET);
            if (tid >= off) incl += t;
        }
        base[tid] = incl - s;
        if (tid == NBUCKET - 1) base[NBUCKET] = incl;
    }
    __syncthreads();   // b2

    // ---- compute (f/m from LDS) + stage into bucket-grouped LDS ----
    #pragma unroll
    for (int it = 0; it < AITER; ++it) {
        if (bkt[it] < 0) continue;
        const int c8 = w * AITER + it;
        const float4 f0 = *(const float4*)&s_fm[(c8 * 4 + 0) * 1024 + lane * 16];
        const float4 f1 = *(const float4*)&s_fm[(c8 * 4 + 1) * 1024 + lane * 16];
        const int4   m0 = *(const int4*)  &s_fm[(c8 * 4 + 2) * 1024 + lane * 16];
        const int4   m1 = *(const int4*)  &s_fm[(c8 * 4 + 3) * 1024 + lane * 16];
        const float vs = props[d_[it].x * 8] * scale;
        const float v0 = m0.x ? vs * fmaxf(f0.x, 0.0f) : 0.0f;
        const float v1 = m0.y ? vs * fmaxf(f0.y, 0.0f) : 0.0f;
        const float v2 = m0.z ? vs * fmaxf(f0.z, 0.0f) : 0.0f;
        const float v3 = m0.w ? vs * fmaxf(f0.w, 0.0f) : 0.0f;
        const float v4 = m1.x ? vs * fmaxf(f1.x, 0.0f) : 0.0f;
        const float v5 = m1.y ? vs * fmaxf(f1.y, 0.0f) : 0.0f;
        const float v6 = m1.z ? vs * fmaxf(f1.z, 0.0f) : 0.0f;
        const float v7 = m1.w ? vs * fmaxf(f1.w, 0.0f) : 0.0f;
        const uint4 rv = make_uint4(pack_bf16_2(v0, v1), pack_bf16_2(v2, v3),
                                    pack_bf16_2(v4, v5), pack_bf16_2(v6, v7));
        const unsigned int pos = base[bkt[it]] + atomicAdd(&cw[w][bkt[it]], 1u);
        s_lidx[pos] = (unsigned short)lidx[it];
        s_val[pos]  = rv;
    }
    __syncthreads();   // b3 (LDS-only)

    // ---- coalesced block-major copy-out ----
    if (tid <= NBUCKET)
        hdrArr[blockIdx.x * 64 + tid] = (unsigned short)base[tid];

    unsigned int* ldst = (unsigned int*)(lidxArr + (size_t)blockIdx.x * BLK_ATOMS);
    const unsigned int* lsrc = (const unsigned int*)s_lidx;
    #pragma unroll
    for (int k = 0; k < BLK_ATOMS / 2 / 256; ++k)
        ldst[k * 256 + tid] = lsrc[k * 256 + tid];

    uint4* vdst = valArr + (size_t)blockIdx.x * BLK_ATOMS;
    #pragma unroll
    for (int k = 0; k < BLK_ATOMS / 256; ++k)
        vdst[k * 256 + tid] = s_val[k * 256 + tid];
}

// K2: accum. Block (bucket, split) walks its source-block range's bucket runs
// (contiguous bursts) into a 32 KiB LDS tile; writes dense partial.
__global__ void __launch_bounds__(256) vdw_accum_kernel(
    const unsigned short* __restrict__ hdrArr,
    const unsigned short* __restrict__ lidxArr,
    const uint4*          __restrict__ valArr,
    float*                __restrict__ partial,
    int nblocks, int nsplit)
{
    __shared__ float acc[LSLOTS];
    const int tid = threadIdx.x;
    for (int k = tid; k < LSLOTS; k += 256) acc[k] = 0.0f;
    __syncthreads();

    const int bucket = blockIdx.x / nsplit;
    const int split  = blockIdx.x % nsplit;
    const int per = (nblocks + nsplit - 1) / nsplit;
    const int b0  = split * per;
    const int b1  = (b0 + per < nblocks) ? (b0 + per) : nblocks;

    const int g    = tid >> 5;    // 8 groups of 32 lanes
    const int lane = tid & 31;

    for (int blk = b0 + g; blk < b1; blk += 8) {
        const int start = hdrArr[blk * 64 + bucket];
        const int end   = hdrArr[blk * 64 + bucket + 1];
        const unsigned short* la = lidxArr + (size_t)blk * BLK_ATOMS;
        const uint4*          va = valArr  + (size_t)blk * BLK_ATOMS;
        for (int rec = start + lane; rec < end; rec += 32) {
            const int   l = la[rec];
            const uint4 v = va[rec];
            float t;
            t = __uint_as_float(v.x << 16);          if (t != 0.0f) atomicAdd(&acc[l + 0], t);
            t = __uint_as_float(v.x & 0xffff0000u);  if (t != 0.0f) atomicAdd(&acc[l + 1], t);
            t = __uint_as_float(v.y << 16);          if (t != 0.0f) atomicAdd(&acc[l + 2], t);
            t = __uint_as_float(v.y & 0xffff0000u);  if (t != 0.0f) atomicAdd(&acc[l + 3], t);
            t = __uint_as_float(v.z << 16);          if (t != 0.0f) atomicAdd(&acc[l + 4], t);
            t = __uint_as_float(v.z & 0xffff0000u);  if (t != 0.0f) atomicAdd(&acc[l + 5], t);
            t = __uint_as_float(v.w << 16);          if (t != 0.0f) atomicAdd(&acc[l + 6], t);
            t = __uint_as_float(v.w & 0xffff0000u);  if (t != 0.0f) atomicAdd(&acc[l + 7], t);
        }
    }
    __syncthreads();

    float* dst = partial + (size_t)blockIdx.x * LSLOTS;
    for (int k = tid; k < LSLOTS; k += 256) dst[k] = acc[k];
}

// K3: merge, float4-vectorized. out[idx..idx+3] = sum over splits.
// Writes every output element (no d_out memset needed).
__global__ void __launch_bounds__(256) vdw_merge_kernel(
    const float* __restrict__ partial,
    float*       __restrict__ out,
    int nsplit)
{
    const int q = blockIdx.x * 256 + threadIdx.x;      // group of 4 floats
    if (q * 4 >= OUT_TOTAL) return;
    const int idx = q * 4;
    const int bb     = idx >> 17;
    const int b      = (idx >> 14) & 7;
    const int c      = (idx >> 12) & 3;
    const int lidx   = bb * 4096 + (idx & 4095);       // 16B-aligned
    const int bucket = b * CDIM + c;
    const float* p = partial + ((size_t)bucket * nsplit) * LSLOTS + lidx;
    float4 s = make_float4(0.f, 0.f, 0.f, 0.f);
    for (int sp = 0; sp < nsplit; ++sp) {
        const float4 v = *(const float4*)(p + (size_t)sp * LSLOTS);
        s.x += v.x; s.y += v.y; s.z += v.z; s.w += v.w;
    }
    *(float4*)&out[idx] = s;
}

// Fallback (small ws): direct global atomics into d_out.
__global__ void __launch_bounds__(256) vdw_atomic_kernel(
    const int*   __restrict__ desc,
    const int*   __restrict__ mask,
    const float* __restrict__ facc,
    const float* __restrict__ props,
    const float* __restrict__ weight,
    float*       __restrict__ out,
    int n)
{
    const int i = blockIdx.x * blockDim.x + threadIdx.x;
    if (i >= n) return;
    const float scale = (1.0f - tanhf(weight[0])) * 0.3f;
    const int4 d = reinterpret_cast<const int4*>(desc)[i];
    if (d.w == -1) return;
    const float vs = props[d.x * 8 + 0] * scale;
    const int   bb = (d.x >= 0 && d.x <= 3) ? 0 : 1;
    float* base = out + bb * OUT_HALF + (((d.y * CDIM + d.z) * RDIM + d.w) * NALT);
    const float4 f0 = reinterpret_cast<const float4*>(facc)[i * 2 + 0];
    const float4 f1 = reinterpret_cast<const float4*>(facc)[i * 2 + 1];
    const int4   m0 = reinterpret_cast<const int4*>(mask)[i * 2 + 0];
    const int4   m1 = reinterpret_cast<const int4*>(mask)[i * 2 + 1];
    if (m0.x) atomicAdd(base + 0, vs * fmaxf(f0.x, 0.0f));
    if (m0.y) atomicAdd(base + 1, vs * fmaxf(f0.y, 0.0f));
    if (m0.z) atomicAdd(base + 2, vs * fmaxf(f0.z, 0.0f));
    if (m0.w) atomicAdd(base + 3, vs * fmaxf(f0.w, 0.0f));
    if (m1.x) atomicAdd(base + 4, vs * fmaxf(f1.x, 0.0f));
    if (m1.y) atomicAdd(base + 5, vs * fmaxf(f1.y, 0.0f));
    if (m1.z) atomicAdd(base + 6, vs * fmaxf(f1.z, 0.0f));
    if (m1.w) atomicAdd(base + 7, vs * fmaxf(f1.w, 0.0f));
}

extern "C" void kernel_launch(void* const* d_in, const int* in_sizes, int n_in,
                              void* d_out, int out_size, void* d_ws, size_t ws_size,
                              hipStream_t stream)
{
    // Inputs per setup_inputs():
    // 0: coords (unused)  1: atom_description (N,4) int32
    // 2: alternativeMask (N,8) int32  3: facc (N,8) f32
    // 4: atom_Properties (500,8) f32  5: weight (1,) f32
    const int*   desc   = (const int*)d_in[1];
    const int*   mask   = (const int*)d_in[2];
    const float* facc   = (const float*)d_in[3];
    const float* props  = (const float*)d_in[4];
    const float* weight = (const float*)d_in[5];
    float*       out    = (float*)d_out;

    const int n       = in_sizes[1] / 4;
    const int nblocks = (n + BLK_ATOMS - 1) / BLK_ATOMS;

    auto align256 = [](size_t x) { return (x + 255) & ~(size_t)255; };
    const size_t off_hdr  = 0;
    const size_t off_lidx = align256(off_hdr  + (size_t)nblocks * 64 * 2);
    const size_t off_val  = align256(off_lidx + (size_t)nblocks * BLK_ATOMS * 2);
    const size_t off_part = align256(off_val  + (size_t)nblocks * BLK_ATOMS * 16);

    int nsplit = 0;
    for (int cand = 16; cand >= 1; cand >>= 1) {
        const size_t need = off_part +
            (size_t)NBUCKET * cand * LSLOTS * sizeof(float);
        if (need <= ws_size) { nsplit = cand; break; }
    }

    if (nsplit >= 1) {
        char* ws = (char*)d_ws;
        unsigned short* hdrArr  = (unsigned short*)(ws + off_hdr);
        unsigned short* lidxArr = (unsigned short*)(ws + off_lidx);
        uint4*          valArr  = (uint4*)(ws + off_val);
        float*          part    = (float*)(ws + off_part);

        vdw_fused_kernel<<<nblocks, 256, 0, stream>>>(
            (const int4*)desc, (const int4*)mask, (const float4*)facc,
            props, weight, hdrArr, lidxArr, valArr, n);

        vdw_accum_kernel<<<NBUCKET * nsplit, 256, 0, stream>>>(
            hdrArr, lidxArr, valArr, part, nblocks, nsplit);

        vdw_merge_kernel<<<(OUT_TOTAL / 4 + 255) / 256, 256, 0, stream>>>(
            part, out, nsplit);
    } else {
        hipMemsetAsync(d_out, 0, (size_t)out_size * sizeof(float), stream);
        vdw_atomic_kernel<<<(n + 255) / 256, 256, 0, stream>>>(
            desc, mask, facc, props, weight, out, n);
    }
}